// Round 1
// baseline (1006.716 us; speedup 1.0000x reference)
//
#include <hip/hip_runtime.h>
#include <hip/hip_cooperative_groups.h>

namespace cg = cooperative_groups;

#define NBLK 256
#define NTHR 256
#define BSZ 64
#define DIM 4096
#define MEM 5
#define MAXIT 50
#define TOL_ 0.01f
#define LAM_ 1e-4f

// workspace layout (float offsets)
#define X_OFF 0
#define F_OFF (BSZ * MEM * DIM)
#define Z_OFF (2 * BSZ * MEM * DIM)
#define A_OFF (Z_OFF + BSZ * DIM)          // alpha[64][8]
#define RP_OFF (A_OFF + BSZ * 8)           // respart[2][256]
#define RES_OFF (RP_OFF + 2 * NBLK)        // res scalar
#define WS_FLOATS (RES_OFF + 16)

// ---------------- GEMM + tanh + residual-partials phase ----------------
// Fk = tanh(Z @ W + x + bias); writes F[:,idx]; per-block residual partials.
// 256 blocks x 16 cols; 4 waves each take a 1024-wide K quarter; lane = row.
__device__ __forceinline__ void gemm_tanh_phase(
    int idx, const float* __restrict__ x, const float* __restrict__ W,
    const float* __restrict__ bias, float* __restrict__ wsf, float* smem)
{
    const int tid = threadIdx.x;
    const int blk = blockIdx.x;
    const int lane = tid & 63;
    const int w = tid >> 6;
    const int jc = blk << 4;  // 16 columns per block
    float* Z = wsf + Z_OFF;
    float* Fs = wsf + F_OFF;
    float* rp = wsf + RP_OFF;

    float4 acc0 = {0.f, 0.f, 0.f, 0.f}, acc1 = acc0, acc2 = acc0, acc3 = acc0;

    for (int chunk = 0; chunk < 16; ++chunk) {
        // stage Z chunk for all 4 wave-quarters: 4 regions x 64 rows x 64 kk
        #pragma unroll
        for (int i = 0; i < 16; ++i) {
            int linear = tid + (i << 8);  // 0..4095 float4s
            int reg = linear >> 10;
            int b = (linear >> 4) & 63;
            int s = linear & 15;
            float4 v = *(const float4*)&Z[b * DIM + (reg << 10) + (chunk << 6) + (s << 2)];
            *(float4*)&smem[(reg << 12) + (b << 6) + ((s ^ (b & 15)) << 2)] = v;
        }
        __syncthreads();
        const int kk0 = (w << 10) + (chunk << 6);
        const float* wr0 = W + (size_t)kk0 * DIM + jc;
        const float* inrow = smem + (w << 12) + (lane << 6);
        const int lx = lane & 15;
        for (int s = 0; s < 16; ++s) {
            float4 in4 = *(const float4*)&inrow[(s ^ lx) << 2];
            const float* wr = wr0 + (size_t)(s << 2) * DIM;
            #pragma unroll
            for (int t = 0; t < 4; ++t) {
                float iv = (t == 0) ? in4.x : (t == 1) ? in4.y : (t == 2) ? in4.z : in4.w;
                const float4* wq = (const float4*)(wr + (size_t)t * DIM);
                float4 w0 = wq[0], w1 = wq[1], w2 = wq[2], w3 = wq[3];
                acc0.x = fmaf(iv, w0.x, acc0.x); acc0.y = fmaf(iv, w0.y, acc0.y);
                acc0.z = fmaf(iv, w0.z, acc0.z); acc0.w = fmaf(iv, w0.w, acc0.w);
                acc1.x = fmaf(iv, w1.x, acc1.x); acc1.y = fmaf(iv, w1.y, acc1.y);
                acc1.z = fmaf(iv, w1.z, acc1.z); acc1.w = fmaf(iv, w1.w, acc1.w);
                acc2.x = fmaf(iv, w2.x, acc2.x); acc2.y = fmaf(iv, w2.y, acc2.y);
                acc2.z = fmaf(iv, w2.z, acc2.z); acc2.w = fmaf(iv, w2.w, acc2.w);
                acc3.x = fmaf(iv, w3.x, acc3.x); acc3.y = fmaf(iv, w3.y, acc3.y);
                acc3.z = fmaf(iv, w3.z, acc3.z); acc3.w = fmaf(iv, w3.w, acc3.w);
            }
        }
        __syncthreads();
    }
    // cross-wave K reduction via LDS: acc_lds[w][row][c], row stride 17 (pad)
    {
        float a[16] = {acc0.x, acc0.y, acc0.z, acc0.w, acc1.x, acc1.y, acc1.z, acc1.w,
                       acc2.x, acc2.y, acc2.z, acc2.w, acc3.x, acc3.y, acc3.z, acc3.w};
        float* arow = smem + w * 1088 + lane * 17;
        #pragma unroll
        for (int c = 0; c < 16; ++c) arow[c] = a[c];
    }
    __syncthreads();
    float lnum = 0.f, lden = 0.f;
    #pragma unroll
    for (int i = 0; i < 4; ++i) {
        int e = tid + (i << 8);  // 0..1023 outputs of this block
        int b = e >> 4, c = e & 15;
        int boff = b * 17 + c;
        float sum = smem[boff] + smem[1088 + boff] + smem[2176 + boff] + smem[3264 + boff];
        int j = jc + c;
        float fz = tanhf(sum + x[(b << 12) + j] + bias[j]);
        float z = Z[(b << 12) + j];
        Fs[(b * MEM + idx) * DIM + j] = fz;
        float d = fz - z;
        lnum = fmaf(d, d, lnum);
        lden = fmaf(fz, fz, lden);
    }
    __syncthreads();
    smem[tid] = lnum;
    smem[NTHR + tid] = lden;
    __syncthreads();
    for (int off = 128; off > 0; off >>= 1) {
        if (tid < off) {
            smem[tid] += smem[tid + off];
            smem[NTHR + tid] += smem[NTHR + tid + off];
        }
        __syncthreads();
    }
    if (tid == 0) {
        rp[blk] = smem[0];
        rp[NBLK + blk] = smem[NTHR];
    }
}

// ---------------- per-batch-row Gram + 6x6 solve ----------------
__device__ void gg_solve_block(int b, int n, float* __restrict__ wsf, float* smem)
{
    const int tid = threadIdx.x;
    const float* Xs = wsf + X_OFF;
    const float* Fs = wsf + F_OFF;
    float* alpha = wsf + A_OFF;
    float gg[15];
    #pragma unroll
    for (int p = 0; p < 15; ++p) gg[p] = 0.f;
    for (int d = tid; d < DIM; d += NTHR) {
        float g[MEM];
        #pragma unroll
        for (int i = 0; i < MEM; ++i) {
            float fv = Fs[(b * MEM + i) * DIM + d];
            float xv = Xs[(b * MEM + i) * DIM + d];
            g[i] = (i < n) ? (fv - xv) : 0.f;
        }
        int p = 0;
        #pragma unroll
        for (int i = 0; i < MEM; ++i)
            #pragma unroll
            for (int q = i; q < MEM; ++q) { gg[p] = fmaf(g[i], g[q], gg[p]); ++p; }
    }
    #pragma unroll
    for (int p = 0; p < 15; ++p) smem[p * NTHR + tid] = gg[p];
    __syncthreads();
    for (int off = 128; off > 0; off >>= 1) {
        if (tid < off) {
            #pragma unroll
            for (int p = 0; p < 15; ++p) smem[p * NTHR + tid] += smem[p * NTHR + tid + off];
        }
        __syncthreads();
    }
    if (tid == 0) {
        float G[MEM][MEM];
        int p = 0;
        for (int i = 0; i < MEM; ++i)
            for (int q = i; q < MEM; ++q) { float v = smem[p * NTHR]; G[i][q] = v; G[q][i] = v; ++p; }
        // H: (m+1)x(m+1) bordered system, identity rows for inactive slots
        float H[6][6], yv[6];
        for (int i = 0; i < 6; ++i) yv[i] = (i == 0) ? 1.f : 0.f;
        H[0][0] = 0.f;
        for (int i = 0; i < MEM; ++i) {
            float mi = (i < n) ? 1.f : 0.f;
            H[0][1 + i] = mi;
            H[1 + i][0] = mi;
        }
        for (int i = 0; i < MEM; ++i)
            for (int q = 0; q < MEM; ++q) {
                float v;
                if (i < n && q < n) v = G[i][q] + ((i == q) ? LAM_ : 0.f);
                else v = (i == q) ? 1.f : 0.f;
                H[1 + i][1 + q] = v;
            }
        // Gaussian elimination, partial pivoting (matches LAPACK-style LU solve)
        for (int col = 0; col < 6; ++col) {
            int piv = col;
            float mv = fabsf(H[col][col]);
            for (int r = col + 1; r < 6; ++r) {
                float av = fabsf(H[r][col]);
                if (av > mv) { mv = av; piv = r; }
            }
            if (piv != col) {
                for (int cc = 0; cc < 6; ++cc) { float tv = H[col][cc]; H[col][cc] = H[piv][cc]; H[piv][cc] = tv; }
                float tv = yv[col]; yv[col] = yv[piv]; yv[piv] = tv;
            }
            float pv = H[col][col];
            for (int r = col + 1; r < 6; ++r) {
                float f = H[r][col] / pv;
                H[r][col] = 0.f;
                for (int cc = col + 1; cc < 6; ++cc) H[r][cc] -= f * H[col][cc];
                yv[r] -= f * yv[col];
            }
        }
        float sol[6];
        for (int col = 5; col >= 0; --col) {
            float s = yv[col];
            for (int cc = col + 1; cc < 6; ++cc) s -= H[col][cc] * sol[cc];
            sol[col] = s / H[col][col];
        }
        for (int i = 0; i < MEM; ++i) alpha[b * 8 + i] = sol[1 + i];
    }
    __syncthreads();
}

// ---------------- persistent Anderson solver ----------------
__global__ __launch_bounds__(NTHR, 1)
void deq_anderson_kernel(const float* __restrict__ x, const float* __restrict__ W,
                         const float* __restrict__ bias, float* __restrict__ out,
                         float* __restrict__ wsf)
{
    cg::grid_group grid = cg::this_grid();
    __shared__ __align__(16) float smem[16384];  // 64 KB
    const int tid = threadIdx.x;
    const int blk = blockIdx.x;
    const int gtid = blk * NTHR + tid;
    float* Xs = wsf + X_OFF;
    float* Fs = wsf + F_OFF;
    float* Z = wsf + Z_OFF;
    float* alpha = wsf + A_OFF;
    float* rp = wsf + RP_OFF;
    volatile float* resp = wsf + RES_OFF;

    // phase A: init. X[:,0]=0, F[:,0]=F0=tanh(x+b), X[:,1]=F0, Z=F0, others 0.
    for (int e = gtid; e < BSZ * DIM; e += NBLK * NTHR) {
        int b = e >> 12, j = e & (DIM - 1);
        float f0 = tanhf(x[e] + bias[j]);
        #pragma unroll
        for (int i = 0; i < MEM; ++i) {
            Xs[(b * MEM + i) * DIM + j] = (i == 1) ? f0 : 0.f;
            Fs[(b * MEM + i) * DIM + j] = (i == 0) ? f0 : 0.f;
        }
        Z[e] = f0;
    }
    grid.sync();
    // F[:,1] = F1 = tanh(F0 @ W + x + b); also residual partials (unused value-wise,
    // only needs to be >= tol, which ||F1-F0|| guarantees)
    gemm_tanh_phase(1, x, W, bias, wsf, smem);
    grid.sync();

    int kend = MAXIT;
    for (int k = 2; k < MAXIT; ++k) {
        const int n = (k < MEM) ? k : MEM;
        if (blk == 0) {
            // deterministic reduction of residual partials from previous body
            smem[tid] = rp[tid];
            smem[NTHR + tid] = rp[NBLK + tid];
            __syncthreads();
            for (int off = 128; off > 0; off >>= 1) {
                if (tid < off) {
                    smem[tid] += smem[tid + off];
                    smem[NTHR + tid] += smem[NTHR + tid + off];
                }
                __syncthreads();
            }
            if (tid == 0) resp[0] = sqrtf(smem[0]) / (1e-5f + sqrtf(smem[NTHR]));
            __syncthreads();
        }
        if (blk < BSZ) gg_solve_block(blk, n, wsf, smem);  // speculative if converged
        grid.sync();
        if (resp[0] < TOL_) { kend = k; break; }
        const int idx = k % MEM;
        // Z = alpha . F (beta == 1), X[:,idx] = Z
        for (int e = gtid; e < BSZ * DIM; e += NBLK * NTHR) {
            int b = e >> 12, j = e & (DIM - 1);
            const float* ab = alpha + b * 8;
            const float* fb = Fs + b * MEM * DIM + j;
            float z = ab[0] * fb[0] + ab[1] * fb[DIM] + ab[2] * fb[2 * DIM] +
                      ab[3] * fb[3 * DIM] + ab[4] * fb[4 * DIM];
            Z[e] = z;
            Xs[(b * MEM + idx) * DIM + j] = z;
        }
        grid.sync();
        gemm_tanh_phase(idx, x, W, bias, wsf, smem);
        grid.sync();
    }

    // output = f(z*) = Fk from last executed body = F[:, (kend-1)%MEM]
    const int fidx = (kend - 1) % MEM;
    for (int e = gtid; e < BSZ * DIM; e += NBLK * NTHR) {
        int b = e >> 12, j = e & (DIM - 1);
        out[e] = Fs[(b * MEM + fidx) * DIM + j];
    }
}

extern "C" void kernel_launch(void* const* d_in, const int* in_sizes, int n_in,
                              void* d_out, int out_size, void* d_ws, size_t ws_size,
                              hipStream_t stream)
{
    (void)in_sizes; (void)n_in; (void)out_size;
    if (ws_size < (size_t)WS_FLOATS * sizeof(float)) return;  // need ~11.6 MB scratch
    const float* x = (const float*)d_in[0];
    const float* W = (const float*)d_in[1];
    const float* b = (const float*)d_in[2];
    float* out = (float*)d_out;
    float* wsf = (float*)d_ws;
    void* args[] = {(void*)&x, (void*)&W, (void*)&b, (void*)&out, (void*)&wsf};
    hipLaunchCooperativeKernel((const void*)deq_anderson_kernel, dim3(NBLK), dim3(NTHR),
                               args, 0, stream);
}

// Round 2
// 814.349 us; speedup vs baseline: 1.2362x; 1.2362x over previous
//
#include <hip/hip_runtime.h>
#include <hip/hip_cooperative_groups.h>

namespace cg = cooperative_groups;

#define NBLK 256
#define NTHR 1024
#define BSZ 64
#define DIM 4096
#define MEM 5
#define MAXIT 50
#define TOL_ 0.01f
#define LAM_ 1e-4f

// workspace layout (float offsets)
#define X_OFF 0
#define F_OFF (BSZ * MEM * DIM)
#define Z_OFF (2 * BSZ * MEM * DIM)
#define RP_OFF (Z_OFF + BSZ * DIM)        // residual partials [2][256]
#define WS_FLOATS (RP_OFF + 2 * NBLK + 16)

// ---------------- GEMM + tanh + residual-partials phase ----------------
// Fk = tanh(Z @ W + x + bias); writes F[:,idx]; per-block residual partials.
// 256 blocks x 16 cols; 16 waves = 4 K-ranges x 4 col-quarters; lane = row.
__device__ __forceinline__ void gemm_tanh_phase(
    int idx, const float* __restrict__ x, const float* __restrict__ W,
    const float* __restrict__ bias, float* __restrict__ wsf, float* smem)
{
    const int tid = threadIdx.x;
    const int blk = blockIdx.x;
    const int lane = tid & 63;
    const int w = tid >> 6;        // 0..15
    const int r = w >> 2;          // K-range (1024 wide)
    const int q = w & 3;           // col quarter (4 cols)
    const int jcq = (blk << 4) + (q << 2);
    float* Z = wsf + Z_OFF;
    float* Fs = wsf + F_OFF;
    float* rp = wsf + RP_OFF;

    float acc0 = 0.f, acc1 = 0.f, acc2 = 0.f, acc3 = 0.f;
    const int lx = lane & 15;
    const float* inrow = smem + (r << 12) + (lane << 6);
    const int srow = tid >> 4;     // staging row 0..63
    const int sg = tid & 15;       // staging granule 0..15

    for (int step = 0; step < 16; ++step) {
        // stage Z[64][64] per K-range region, XOR-granule swizzle (v1 pattern)
        #pragma unroll
        for (int i = 0; i < 4; ++i) {
            float4 v = *(const float4*)&Z[srow * DIM + (i << 10) + (step << 6) + (sg << 2)];
            *(float4*)&smem[(i << 12) + (srow << 6) + ((sg ^ (srow & 15)) << 2)] = v;
        }
        __syncthreads();
        const float* wbase = W + (size_t)((r << 10) + (step << 6)) * DIM + jcq;
        #pragma unroll 2
        for (int s = 0; s < 16; ++s) {
            float4 in4 = *(const float4*)&inrow[(s ^ lx) << 2];
            const float* wr = wbase + (size_t)(s << 2) * DIM;
            #pragma unroll
            for (int t = 0; t < 4; ++t) {
                float iv = (t == 0) ? in4.x : (t == 1) ? in4.y : (t == 2) ? in4.z : in4.w;
                float4 wq = *(const float4*)(wr + (size_t)t * DIM);
                acc0 = fmaf(iv, wq.x, acc0);
                acc1 = fmaf(iv, wq.y, acc1);
                acc2 = fmaf(iv, wq.z, acc2);
                acc3 = fmaf(iv, wq.w, acc3);
            }
        }
        __syncthreads();
    }
    // cross-K-range reduce: red[4][64][17] (pad 17 -> conflict-free)
    {
        float* rrow = smem + r * 1088 + lane * 17 + (q << 2);
        rrow[0] = acc0; rrow[1] = acc1; rrow[2] = acc2; rrow[3] = acc3;
    }
    __syncthreads();
    const int row = tid >> 4, cc = tid & 15;
    const int boff = row * 17 + cc;
    float sum = smem[boff] + smem[1088 + boff] + smem[2176 + boff] + smem[3264 + boff];
    const int j = (blk << 4) + cc;
    float fz = tanhf(sum + x[(row << 12) + j] + bias[j]);
    Fs[(row * MEM + idx) * DIM + j] = fz;
    float d = fz - Z[(row << 12) + j];
    float lnum = d * d, lden = fz * fz;
    #pragma unroll
    for (int off = 1; off < 64; off <<= 1) {
        lnum += __shfl_xor(lnum, off, 64);
        lden += __shfl_xor(lden, off, 64);
    }
    if (lane == 0) { smem[8192 + w] = lnum; smem[8208 + w] = lden; }
    __syncthreads();
    if (tid == 0) {
        float a = 0.f, b2 = 0.f;
        for (int i = 0; i < 16; ++i) { a += smem[8192 + i]; b2 += smem[8208 + i]; }
        rp[blk] = a;
        rp[NBLK + blk] = b2;
    }
}

// ---------------- residual reduce (every block, deterministic) -----------
__device__ __forceinline__ float phase_res(const float* __restrict__ rp, float* smem)
{
    const int tid = threadIdx.x;
    const int lane = tid & 63, w = tid >> 6;
    float a = (tid < NBLK) ? rp[tid] : 0.f;
    float b = (tid < NBLK) ? rp[NBLK + tid] : 0.f;
    #pragma unroll
    for (int off = 1; off < 64; off <<= 1) {
        a += __shfl_xor(a, off, 64);
        b += __shfl_xor(b, off, 64);
    }
    if (lane == 0) { smem[w] = a; smem[16 + w] = b; }
    __syncthreads();
    if (tid == 0) {
        float sa = 0.f, sb = 0.f;
        for (int i = 0; i < 16; ++i) { sa += smem[i]; sb += smem[16 + i]; }
        smem[32] = sqrtf(sa) / (1e-5f + sqrtf(sb));
    }
    __syncthreads();
    float res = smem[32];
    __syncthreads();
    return res;
}

// ---- per-batch-row: Gram + 6x6 bordered solve + alpha-combine (fused) ----
__device__ void gram_solve_combine(int b, int n, int idx, float* __restrict__ wsf,
                                   float* smem)
{
    const int tid = threadIdx.x;
    const int lane = tid & 63, w = tid >> 6;
    float* Xs = wsf + X_OFF;
    float* Fs = wsf + F_OFF;
    float* Z = wsf + Z_OFF;
    const int j4 = tid << 2;

    float g[MEM][4];
    #pragma unroll
    for (int i = 0; i < MEM; ++i) {
        float4 fv = *(const float4*)&Fs[(b * MEM + i) * DIM + j4];
        float4 xv = *(const float4*)&Xs[(b * MEM + i) * DIM + j4];
        bool act = (i < n);
        g[i][0] = act ? (fv.x - xv.x) : 0.f;
        g[i][1] = act ? (fv.y - xv.y) : 0.f;
        g[i][2] = act ? (fv.z - xv.z) : 0.f;
        g[i][3] = act ? (fv.w - xv.w) : 0.f;
    }
    float gg[15];
    {
        int p = 0;
        #pragma unroll
        for (int i = 0; i < MEM; ++i)
            #pragma unroll
            for (int qq = i; qq < MEM; ++qq) {
                float s = 0.f;
                #pragma unroll
                for (int c = 0; c < 4; ++c) s = fmaf(g[i][c], g[qq][c], s);
                gg[p++] = s;
            }
    }
    #pragma unroll
    for (int off = 1; off < 64; off <<= 1)
        #pragma unroll
        for (int p = 0; p < 15; ++p) gg[p] += __shfl_xor(gg[p], off, 64);
    if (lane == 0) {
        #pragma unroll
        for (int p = 0; p < 15; ++p) smem[p * 16 + w] = gg[p];
    }
    __syncthreads();
    if (tid == 0) {
        float G[MEM][MEM];
        int p = 0;
        for (int i = 0; i < MEM; ++i)
            for (int qq = i; qq < MEM; ++qq) {
                float v = 0.f;
                for (int ww = 0; ww < 16; ++ww) v += smem[p * 16 + ww];
                G[i][qq] = v; G[qq][i] = v; ++p;
            }
        float H[6][6], yv[6];
        for (int i = 0; i < 6; ++i) yv[i] = (i == 0) ? 1.f : 0.f;
        H[0][0] = 0.f;
        for (int i = 0; i < MEM; ++i) {
            float mi = (i < n) ? 1.f : 0.f;
            H[0][1 + i] = mi;
            H[1 + i][0] = mi;
        }
        for (int i = 0; i < MEM; ++i)
            for (int qq = 0; qq < MEM; ++qq) {
                float v;
                if (i < n && qq < n) v = G[i][qq] + ((i == qq) ? LAM_ : 0.f);
                else v = (i == qq) ? 1.f : 0.f;
                H[1 + i][1 + qq] = v;
            }
        for (int col = 0; col < 6; ++col) {
            int piv = col;
            float mv = fabsf(H[col][col]);
            for (int rr = col + 1; rr < 6; ++rr) {
                float av = fabsf(H[rr][col]);
                if (av > mv) { mv = av; piv = rr; }
            }
            if (piv != col) {
                for (int c2 = 0; c2 < 6; ++c2) { float tv = H[col][c2]; H[col][c2] = H[piv][c2]; H[piv][c2] = tv; }
                float tv = yv[col]; yv[col] = yv[piv]; yv[piv] = tv;
            }
            float pv = H[col][col];
            for (int rr = col + 1; rr < 6; ++rr) {
                float f = H[rr][col] / pv;
                H[rr][col] = 0.f;
                for (int c2 = col + 1; c2 < 6; ++c2) H[rr][c2] -= f * H[col][c2];
                yv[rr] -= f * yv[col];
            }
        }
        float sol[6];
        for (int col = 5; col >= 0; --col) {
            float s = yv[col];
            for (int c2 = col + 1; c2 < 6; ++c2) s -= H[col][c2] * sol[c2];
            sol[col] = s / H[col][col];
        }
        for (int i = 0; i < MEM; ++i) smem[240 + i] = sol[1 + i];
    }
    __syncthreads();
    float al[MEM];
    #pragma unroll
    for (int i = 0; i < MEM; ++i) al[i] = smem[240 + i];
    float4 zf = {0.f, 0.f, 0.f, 0.f};
    #pragma unroll
    for (int i = 0; i < MEM; ++i) {
        float4 fv = *(const float4*)&Fs[(b * MEM + i) * DIM + j4];
        zf.x = fmaf(al[i], fv.x, zf.x);
        zf.y = fmaf(al[i], fv.y, zf.y);
        zf.z = fmaf(al[i], fv.z, zf.z);
        zf.w = fmaf(al[i], fv.w, zf.w);
    }
    *(float4*)&Z[(b << 12) + j4] = zf;
    *(float4*)&Xs[(b * MEM + idx) * DIM + j4] = zf;
}

// ---------------- persistent Anderson solver ----------------
__global__ __launch_bounds__(NTHR, 4)
void deq_anderson_kernel(const float* __restrict__ x, const float* __restrict__ W,
                         const float* __restrict__ bias, float* __restrict__ out,
                         float* __restrict__ wsf)
{
    cg::grid_group grid = cg::this_grid();
    __shared__ __align__(16) float smem[16384];  // 64 KB
    const int tid = threadIdx.x;
    const int blk = blockIdx.x;
    const int e = blk * NTHR + tid;  // exactly one element per thread
    const int b = e >> 12, j = e & (DIM - 1);
    float* Xs = wsf + X_OFF;
    float* Fs = wsf + F_OFF;
    float* Z = wsf + Z_OFF;

    // init: X[:,0]=0, X[:,1]=F0, F[:,0]=F0=tanh(x+b), Z=F0, others 0
    {
        float f0 = tanhf(x[e] + bias[j]);
        #pragma unroll
        for (int i = 0; i < MEM; ++i) {
            Xs[(b * MEM + i) * DIM + j] = (i == 1) ? f0 : 0.f;
            Fs[(b * MEM + i) * DIM + j] = (i == 0) ? f0 : 0.f;
        }
        Z[e] = f0;
    }
    grid.sync();
    gemm_tanh_phase(1, x, W, bias, wsf, smem);  // F[:,1] = F1 = f(F0)
    grid.sync();

    int kend = MAXIT;
    for (int k = 2; k < MAXIT; ++k) {
        float res = phase_res(wsf + RP_OFF, smem);   // uniform across grid
        if (k > 2 && res < TOL_) { kend = k; break; }
        const int n = (k < MEM) ? k : MEM;
        const int idx = k % MEM;
        if (blk < BSZ) gram_solve_combine(blk, n, idx, wsf, smem);
        grid.sync();
        gemm_tanh_phase(idx, x, W, bias, wsf, smem);
        grid.sync();
    }

    const int fidx = (kend - 1) % MEM;
    out[e] = Fs[(b * MEM + fidx) * DIM + j];
}

extern "C" void kernel_launch(void* const* d_in, const int* in_sizes, int n_in,
                              void* d_out, int out_size, void* d_ws, size_t ws_size,
                              hipStream_t stream)
{
    (void)in_sizes; (void)n_in; (void)out_size;
    if (ws_size < (size_t)WS_FLOATS * sizeof(float)) return;
    const float* x = (const float*)d_in[0];
    const float* W = (const float*)d_in[1];
    const float* b = (const float*)d_in[2];
    float* out = (float*)d_out;
    float* wsf = (float*)d_ws;
    void* args[] = {(void*)&x, (void*)&W, (void*)&b, (void*)&out, (void*)&wsf};
    hipLaunchCooperativeKernel((const void*)deq_anderson_kernel, dim3(NBLK), dim3(NTHR),
                               args, 0, stream);
}

// Round 3
// 447.962 us; speedup vs baseline: 2.2473x; 1.8179x over previous
//
#include <hip/hip_runtime.h>
#include <hip/hip_cooperative_groups.h>

namespace cg = cooperative_groups;

#define NBLK 256
#define NTHR 1024
#define BSZ 64
#define DIM 4096
#define MEM 5
#define MAXIT 50
#define TOL_ 0.01f
#define LAM_ 1e-4f

// float-region workspace layout (float offsets) — identical to round-2
#define X_OFF 0
#define F_OFF (BSZ * MEM * DIM)
#define Z_OFF (2 * BSZ * MEM * DIM)
#define RP_OFF (Z_OFF + BSZ * DIM)              // residual partials [2][256]
#define FP32_WS_FLOATS (RP_OFF + 2 * NBLK + 16)
// bf16 regions appended (byte offsets)
#define ZH_BYTE ((size_t)(RP_OFF + 1024) * 4)
#define ZL_BYTE (ZH_BYTE + (size_t)BSZ * DIM * 2)
#define WH_BYTE (ZL_BYTE + (size_t)BSZ * DIM * 2)
#define WL_BYTE (WH_BYTE + (size_t)DIM * DIM * 2)
#define WS_NEED (WL_BYTE + (size_t)DIM * DIM * 2)

typedef __attribute__((ext_vector_type(8))) short short8v;   // 8 bf16
typedef __attribute__((ext_vector_type(4))) float f32x4;

__device__ __forceinline__ unsigned short f2bf(float f) {
    unsigned int u = __float_as_uint(f);
    u = (u + 0x7fffu + ((u >> 16) & 1u)) >> 16;
    return (unsigned short)u;
}
__device__ __forceinline__ float bf2f(unsigned short h) {
    return __uint_as_float(((unsigned int)h) << 16);
}

// ---------------- one-time W -> packed double-bf16 conversion ----------------
// Wh/Wl element order: ((ng*128 + ks)*64 + lane)*8 + e  where
// k = ks*32 + (lane>>4)*8 + e, j = ng*16 + (lane&15)  (B-fragment order).
__device__ void convert_w(const float* __restrict__ W, unsigned short* __restrict__ Wh,
                          unsigned short* __restrict__ Wl, float* smem)
{
    const int tid = threadIdx.x;
    const int blk = blockIdx.x;
    const int jc = blk << 4;
    for (int sc = 0; sc < 8; ++sc) {   // 8 super-chunks of 512 k-rows
        __syncthreads();
        #pragma unroll
        for (int h = 0; h < 2; ++h) {
            int rrow = (tid >> 2) + (h << 8);          // 0..511
            int seg = tid & 3;
            float4 v = *(const float4*)&W[(size_t)((sc << 9) + rrow) * DIM + jc + (seg << 2)];
            float* dst = smem + rrow * 17 + (seg << 2);
            dst[0] = v.x; dst[1] = v.y; dst[2] = v.z; dst[3] = v.w;
        }
        __syncthreads();
        unsigned int* oh = (unsigned int*)(Wh + ((size_t)blk * 128 + sc * 16) * 512);
        unsigned int* ol = (unsigned int*)(Wl + ((size_t)blk * 128 + sc * 16) * 512);
        #pragma unroll
        for (int it = 0; it < 4; ++it) {
            int o = tid + (it << 10);                  // 0..4095
            int ksl = o >> 8, ln = (o >> 2) & 63, ep = o & 3;
            int kl = (ksl << 5) + ((ln >> 4) << 3) + (ep << 1);
            float w0 = smem[kl * 17 + (ln & 15)];
            float w1 = smem[(kl + 1) * 17 + (ln & 15)];
            unsigned short h0 = f2bf(w0), h1 = f2bf(w1);
            unsigned short l0 = f2bf(w0 - bf2f(h0)), l1 = f2bf(w1 - bf2f(h1));
            oh[o] = (unsigned int)h0 | ((unsigned int)h1 << 16);
            ol[o] = (unsigned int)l0 | ((unsigned int)l1 << 16);
        }
    }
    __syncthreads();
}

// ---------------- MFMA GEMM + tanh + residual partials ----------------
// Fk = tanh(Z @ W + x + b), double-bf16: zh*wh + zh*wl + zl*wh, fp32 acc.
// 256 blocks x 16 cols, 16 waves K-split 16-way (8 ksteps of 32 each).
__device__ __forceinline__ void gemm_tanh_mfma(
    int idx, const float* __restrict__ x, const float* __restrict__ bias,
    const unsigned short* __restrict__ Zh, const unsigned short* __restrict__ Zl,
    const unsigned short* __restrict__ Wh, const unsigned short* __restrict__ Wl,
    float* __restrict__ Z, float* __restrict__ Fs, float* __restrict__ rp, float* smem)
{
    const int tid = threadIdx.x;
    const int blk = blockIdx.x;
    const int lane = tid & 63;
    const int w = tid >> 6;                 // wave 0..15
    const int r0 = lane & 15;               // A row-local / B col-local
    const int kg = lane >> 4;               // k-group 0..3
    f32x4 acc[4] = {f32x4{0,0,0,0}, f32x4{0,0,0,0}, f32x4{0,0,0,0}, f32x4{0,0,0,0}};

    const unsigned short* bh = Wh + (size_t)blk * 65536;
    const unsigned short* bl = Wl + (size_t)blk * 65536;
    const int ksbase = w << 3;
    #pragma unroll 2
    for (int s = 0; s < 8; ++s) {
        const int ks = ksbase + s;
        const int kbase = (ks << 5) + (kg << 3);
        short8v Bh = *(const short8v*)(bh + ((size_t)ks << 9) + (lane << 3));
        short8v Bl = *(const short8v*)(bl + ((size_t)ks << 9) + (lane << 3));
        #pragma unroll
        for (int m = 0; m < 4; ++m) {
            const size_t ao = (size_t)((m << 4) + r0) * DIM + kbase;
            short8v Ah = *(const short8v*)(Zh + ao);
            short8v Al = *(const short8v*)(Zl + ao);
            acc[m] = __builtin_amdgcn_mfma_f32_16x16x32_bf16(Ah, Bh, acc[m], 0, 0, 0);
            acc[m] = __builtin_amdgcn_mfma_f32_16x16x32_bf16(Ah, Bl, acc[m], 0, 0, 0);
            acc[m] = __builtin_amdgcn_mfma_f32_16x16x32_bf16(Al, Bh, acc[m], 0, 0, 0);
        }
    }
    // cross-wave reduce: sections stride 1028 floats (banks spread by 4/section),
    // 2 rounds of 8 sections to stay within LDS budget.
    const int row = tid >> 4, cc = tid & 15;
    const int m_o = row >> 4, rl = row & 15;
    const int lsrc = cc + ((rl >> 2) << 4), reg = rl & 3;
    float sum = 0.f;
    #pragma unroll
    for (int rnd = 0; rnd < 2; ++rnd) {
        __syncthreads();
        if ((w >> 3) == rnd) {
            float* sec = smem + (w & 7) * 1028;
            #pragma unroll
            for (int m = 0; m < 4; ++m)
                *(f32x4*)(sec + (m << 8) + (lane << 2)) = acc[m];
        }
        __syncthreads();
        #pragma unroll
        for (int p = 0; p < 8; ++p)
            sum += smem[p * 1028 + (m_o << 8) + (lsrc << 2) + reg];
    }
    // epilogue: tanh, F-slot write, residual partials
    const int j = (blk << 4) + cc;
    float fz = tanhf(sum + x[(row << 12) + j] + bias[j]);
    Fs[(row * MEM + idx) * DIM + j] = fz;
    float d = fz - Z[(row << 12) + j];
    float lnum = d * d, lden = fz * fz;
    #pragma unroll
    for (int off = 1; off < 64; off <<= 1) {
        lnum += __shfl_xor(lnum, off, 64);
        lden += __shfl_xor(lden, off, 64);
    }
    if (lane == 0) { smem[8448 + w] = lnum; smem[8480 + w] = lden; }
    __syncthreads();
    if (tid == 0) {
        float a = 0.f, b2 = 0.f;
        #pragma unroll
        for (int i = 0; i < 16; ++i) { a += smem[8448 + i]; b2 += smem[8480 + i]; }
        rp[blk] = a;
        rp[NBLK + blk] = b2;
    }
}

// ---------------- fp32 fallback GEMM (round-2, proven) ----------------
__device__ __forceinline__ void gemm_tanh_fp32(
    int idx, const float* __restrict__ x, const float* __restrict__ W,
    const float* __restrict__ bias, float* __restrict__ wsf, float* smem)
{
    const int tid = threadIdx.x;
    const int blk = blockIdx.x;
    const int lane = tid & 63;
    const int w = tid >> 6;
    const int r = w >> 2;
    const int q = w & 3;
    const int jcq = (blk << 4) + (q << 2);
    float* Z = wsf + Z_OFF;
    float* Fs = wsf + F_OFF;
    float* rp = wsf + RP_OFF;

    float acc0 = 0.f, acc1 = 0.f, acc2 = 0.f, acc3 = 0.f;
    const int lx = lane & 15;
    const float* inrow = smem + (r << 12) + (lane << 6);
    const int srow = tid >> 4;
    const int sg = tid & 15;

    for (int step = 0; step < 16; ++step) {
        #pragma unroll
        for (int i = 0; i < 4; ++i) {
            float4 v = *(const float4*)&Z[srow * DIM + (i << 10) + (step << 6) + (sg << 2)];
            *(float4*)&smem[(i << 12) + (srow << 6) + ((sg ^ (srow & 15)) << 2)] = v;
        }
        __syncthreads();
        const float* wbase = W + (size_t)((r << 10) + (step << 6)) * DIM + jcq;
        #pragma unroll 2
        for (int s = 0; s < 16; ++s) {
            float4 in4 = *(const float4*)&inrow[(s ^ lx) << 2];
            const float* wr = wbase + (size_t)(s << 2) * DIM;
            #pragma unroll
            for (int t = 0; t < 4; ++t) {
                float iv = (t == 0) ? in4.x : (t == 1) ? in4.y : (t == 2) ? in4.z : in4.w;
                float4 wq = *(const float4*)(wr + (size_t)t * DIM);
                acc0 = fmaf(iv, wq.x, acc0);
                acc1 = fmaf(iv, wq.y, acc1);
                acc2 = fmaf(iv, wq.z, acc2);
                acc3 = fmaf(iv, wq.w, acc3);
            }
        }
        __syncthreads();
    }
    {
        float* rrow = smem + r * 1088 + lane * 17 + (q << 2);
        rrow[0] = acc0; rrow[1] = acc1; rrow[2] = acc2; rrow[3] = acc3;
    }
    __syncthreads();
    const int row = tid >> 4, cc = tid & 15;
    const int boff = row * 17 + cc;
    float sum = smem[boff] + smem[1088 + boff] + smem[2176 + boff] + smem[3264 + boff];
    const int j = (blk << 4) + cc;
    float fz = tanhf(sum + x[(row << 12) + j] + bias[j]);
    Fs[(row * MEM + idx) * DIM + j] = fz;
    float d = fz - Z[(row << 12) + j];
    float lnum = d * d, lden = fz * fz;
    #pragma unroll
    for (int off = 1; off < 64; off <<= 1) {
        lnum += __shfl_xor(lnum, off, 64);
        lden += __shfl_xor(lden, off, 64);
    }
    if (lane == 0) { smem[8448 + w] = lnum; smem[8480 + w] = lden; }
    __syncthreads();
    if (tid == 0) {
        float a = 0.f, b2 = 0.f;
        for (int i = 0; i < 16; ++i) { a += smem[8448 + i]; b2 += smem[8480 + i]; }
        rp[blk] = a;
        rp[NBLK + blk] = b2;
    }
}

// ---------------- residual reduce (every block, deterministic) -----------
__device__ __forceinline__ float phase_res(const float* __restrict__ rp, float* smem)
{
    const int tid = threadIdx.x;
    const int lane = tid & 63, w = tid >> 6;
    float a = (tid < NBLK) ? rp[tid] : 0.f;
    float b = (tid < NBLK) ? rp[NBLK + tid] : 0.f;
    #pragma unroll
    for (int off = 1; off < 64; off <<= 1) {
        a += __shfl_xor(a, off, 64);
        b += __shfl_xor(b, off, 64);
    }
    if (lane == 0) { smem[w] = a; smem[16 + w] = b; }
    __syncthreads();
    if (tid == 0) {
        float sa = 0.f, sb = 0.f;
        for (int i = 0; i < 16; ++i) { sa += smem[i]; sb += smem[16 + i]; }
        smem[32] = sqrtf(sa) / (1e-5f + sqrtf(sb));
    }
    __syncthreads();
    float res = smem[32];
    __syncthreads();
    return res;
}

// ---- per-batch-row: Gram + 6x6 bordered solve + alpha-combine (fused) ----
template <bool BF16>
__device__ void gram_solve_combine(int b, int n, int idx, float* __restrict__ wsf,
                                   unsigned short* __restrict__ Zh,
                                   unsigned short* __restrict__ Zl, float* smem)
{
    const int tid = threadIdx.x;
    const int lane = tid & 63, w = tid >> 6;
    float* Xs = wsf + X_OFF;
    float* Fs = wsf + F_OFF;
    float* Z = wsf + Z_OFF;
    const int j4 = tid << 2;

    float g[MEM][4];
    #pragma unroll
    for (int i = 0; i < MEM; ++i) {
        float4 fv = *(const float4*)&Fs[(b * MEM + i) * DIM + j4];
        float4 xv = *(const float4*)&Xs[(b * MEM + i) * DIM + j4];
        bool act = (i < n);
        g[i][0] = act ? (fv.x - xv.x) : 0.f;
        g[i][1] = act ? (fv.y - xv.y) : 0.f;
        g[i][2] = act ? (fv.z - xv.z) : 0.f;
        g[i][3] = act ? (fv.w - xv.w) : 0.f;
    }
    float gg[15];
    {
        int p = 0;
        #pragma unroll
        for (int i = 0; i < MEM; ++i)
            #pragma unroll
            for (int qq = i; qq < MEM; ++qq) {
                float s = 0.f;
                #pragma unroll
                for (int c = 0; c < 4; ++c) s = fmaf(g[i][c], g[qq][c], s);
                gg[p++] = s;
            }
    }
    #pragma unroll
    for (int off = 1; off < 64; off <<= 1)
        #pragma unroll
        for (int p = 0; p < 15; ++p) gg[p] += __shfl_xor(gg[p], off, 64);
    if (lane == 0) {
        #pragma unroll
        for (int p = 0; p < 15; ++p) smem[p * 16 + w] = gg[p];
    }
    __syncthreads();
    if (tid == 0) {
        float G[MEM][MEM];
        int p = 0;
        for (int i = 0; i < MEM; ++i)
            for (int qq = i; qq < MEM; ++qq) {
                float v = 0.f;
                for (int ww = 0; ww < 16; ++ww) v += smem[p * 16 + ww];
                G[i][qq] = v; G[qq][i] = v; ++p;
            }
        float H[6][6], yv[6];
        for (int i = 0; i < 6; ++i) yv[i] = (i == 0) ? 1.f : 0.f;
        H[0][0] = 0.f;
        for (int i = 0; i < MEM; ++i) {
            float mi = (i < n) ? 1.f : 0.f;
            H[0][1 + i] = mi;
            H[1 + i][0] = mi;
        }
        for (int i = 0; i < MEM; ++i)
            for (int qq = 0; qq < MEM; ++qq) {
                float v;
                if (i < n && qq < n) v = G[i][qq] + ((i == qq) ? LAM_ : 0.f);
                else v = (i == qq) ? 1.f : 0.f;
                H[1 + i][1 + qq] = v;
            }
        for (int col = 0; col < 6; ++col) {
            int piv = col;
            float mv = fabsf(H[col][col]);
            for (int rr = col + 1; rr < 6; ++rr) {
                float av = fabsf(H[rr][col]);
                if (av > mv) { mv = av; piv = rr; }
            }
            if (piv != col) {
                for (int c2 = 0; c2 < 6; ++c2) { float tv = H[col][c2]; H[col][c2] = H[piv][c2]; H[piv][c2] = tv; }
                float tv = yv[col]; yv[col] = yv[piv]; yv[piv] = tv;
            }
            float pv = H[col][col];
            for (int rr = col + 1; rr < 6; ++rr) {
                float f = H[rr][col] / pv;
                H[rr][col] = 0.f;
                for (int c2 = col + 1; c2 < 6; ++c2) H[rr][c2] -= f * H[col][c2];
                yv[rr] -= f * yv[col];
            }
        }
        float sol[6];
        for (int col = 5; col >= 0; --col) {
            float s = yv[col];
            for (int c2 = col + 1; c2 < 6; ++c2) s -= H[col][c2] * sol[c2];
            sol[col] = s / H[col][col];
        }
        for (int i = 0; i < MEM; ++i) smem[240 + i] = sol[1 + i];
    }
    __syncthreads();
    float al[MEM];
    #pragma unroll
    for (int i = 0; i < MEM; ++i) al[i] = smem[240 + i];
    float4 zf = {0.f, 0.f, 0.f, 0.f};
    #pragma unroll
    for (int i = 0; i < MEM; ++i) {
        float4 fv = *(const float4*)&Fs[(b * MEM + i) * DIM + j4];
        zf.x = fmaf(al[i], fv.x, zf.x);
        zf.y = fmaf(al[i], fv.y, zf.y);
        zf.z = fmaf(al[i], fv.z, zf.z);
        zf.w = fmaf(al[i], fv.w, zf.w);
    }
    *(float4*)&Z[(b << 12) + j4] = zf;
    *(float4*)&Xs[(b * MEM + idx) * DIM + j4] = zf;
    if constexpr (BF16) {
        float zz[4] = {zf.x, zf.y, zf.z, zf.w};
        unsigned short h[4], l[4];
        #pragma unroll
        for (int c = 0; c < 4; ++c) {
            h[c] = f2bf(zz[c]);
            l[c] = f2bf(zz[c] - bf2f(h[c]));
        }
        unsigned int* zh32 = (unsigned int*)(Zh + ((size_t)b << 12) + j4);
        unsigned int* zl32 = (unsigned int*)(Zl + ((size_t)b << 12) + j4);
        zh32[0] = (unsigned int)h[0] | ((unsigned int)h[1] << 16);
        zh32[1] = (unsigned int)h[2] | ((unsigned int)h[3] << 16);
        zl32[0] = (unsigned int)l[0] | ((unsigned int)l[1] << 16);
        zl32[1] = (unsigned int)l[2] | ((unsigned int)l[3] << 16);
    }
}

// ---------------- persistent Anderson solver ----------------
template <bool BF16>
__global__ __launch_bounds__(NTHR, 4)
void deq_anderson(const float* __restrict__ x, const float* __restrict__ W,
                  const float* __restrict__ bias, float* __restrict__ out,
                  char* __restrict__ ws)
{
    cg::grid_group grid = cg::this_grid();
    __shared__ __align__(16) float smem[16384];  // 64 KB
    float* wsf = (float*)ws;
    unsigned short* Zh = (unsigned short*)(ws + ZH_BYTE);
    unsigned short* Zl = (unsigned short*)(ws + ZL_BYTE);
    unsigned short* Wh = (unsigned short*)(ws + WH_BYTE);
    unsigned short* Wl = (unsigned short*)(ws + WL_BYTE);
    const int tid = threadIdx.x;
    const int blk = blockIdx.x;
    const int e = blk * NTHR + tid;
    const int b = e >> 12, j = e & (DIM - 1);
    float* Xs = wsf + X_OFF;
    float* Fs = wsf + F_OFF;
    float* Z = wsf + Z_OFF;

    // init: X[:,0]=0, X[:,1]=F0, F[:,0]=F0=tanh(x+b), Z=F0
    {
        float f0 = tanhf(x[e] + bias[j]);
        #pragma unroll
        for (int i = 0; i < MEM; ++i) {
            Xs[(b * MEM + i) * DIM + j] = (i == 1) ? f0 : 0.f;
            Fs[(b * MEM + i) * DIM + j] = (i == 0) ? f0 : 0.f;
        }
        Z[e] = f0;
        if constexpr (BF16) {
            unsigned short h = f2bf(f0);
            Zh[e] = h;
            Zl[e] = f2bf(f0 - bf2f(h));
        }
    }
    if constexpr (BF16) convert_w(W, Wh, Wl, smem);
    grid.sync();
    if constexpr (BF16)
        gemm_tanh_mfma(1, x, bias, Zh, Zl, Wh, Wl, Z, Fs, wsf + RP_OFF, smem);
    else
        gemm_tanh_fp32(1, x, W, bias, wsf, smem);
    grid.sync();

    int kend = MAXIT;
    for (int k = 2; k < MAXIT; ++k) {
        float res = phase_res(wsf + RP_OFF, smem);
        if (k > 2 && res < TOL_) { kend = k; break; }
        const int n = (k < MEM) ? k : MEM;
        const int idx = k % MEM;
        if (blk < BSZ) gram_solve_combine<BF16>(blk, n, idx, wsf, Zh, Zl, smem);
        grid.sync();
        if constexpr (BF16)
            gemm_tanh_mfma(idx, x, bias, Zh, Zl, Wh, Wl, Z, Fs, wsf + RP_OFF, smem);
        else
            gemm_tanh_fp32(idx, x, W, bias, wsf, smem);
        grid.sync();
    }

    const int fidx = (kend - 1) % MEM;
    out[e] = Fs[(b * MEM + fidx) * DIM + j];
}

extern "C" void kernel_launch(void* const* d_in, const int* in_sizes, int n_in,
                              void* d_out, int out_size, void* d_ws, size_t ws_size,
                              hipStream_t stream)
{
    (void)in_sizes; (void)n_in; (void)out_size;
    if (ws_size < (size_t)FP32_WS_FLOATS * sizeof(float)) return;
    const float* x = (const float*)d_in[0];
    const float* W = (const float*)d_in[1];
    const float* b = (const float*)d_in[2];
    float* out = (float*)d_out;
    char* ws = (char*)d_ws;
    void* args[] = {(void*)&x, (void*)&W, (void*)&b, (void*)&out, (void*)&ws};
    const void* fn = (ws_size >= WS_NEED)
                         ? reinterpret_cast<const void*>(&deq_anderson<true>)
                         : reinterpret_cast<const void*>(&deq_anderson<false>);
    hipLaunchCooperativeKernel(fn, dim3(NBLK), dim3(NTHR), args, 0, stream);
}